// Round 1
// baseline (128.281 us; speedup 1.0000x reference)
//
#include <hip/hip_runtime.h>

// DisplaceChannel: out[b,p,c,h,w] = in[b,p,c, h-off_y[p], w-off_x[p]] (0 if OOB)
// B=16, P=9, C/P=32 (C=288), H=W=64. Offsets are multiples of 32 -> float4
// vectors stay aligned and validity is uniform per vector.

#define B_   16
#define C_   288
#define H_   64
#define W_   64

__global__ __launch_bounds__(256) void displace_kernel(
    const float* __restrict__ inp,
    const int*   __restrict__ offs,
    float*       __restrict__ out)
{
    const int bc = blockIdx.x;            // [0, B_*C_)
    const int c  = bc % C_;               // once per block (uniform)
    const int p  = c >> 5;                // CHAN_PER_POS = 32
    const int off_x = offs[2 * p];        // block-uniform scalar loads
    const int off_y = offs[2 * p + 1];

    const float4* __restrict__ src = (const float4*)(inp + (size_t)bc * (H_ * W_));
    float4* __restrict__ dst       = (float4*)(out + (size_t)bc * (H_ * W_));

    // H_*W_/4 = 1024 float4 per plane; 256 threads x 4 iterations.
    #pragma unroll
    for (int k = 0; k < 4; ++k) {
        const int v  = k * 256 + threadIdx.x;   // [0, 1024)
        const int h  = v >> 4;                  // row
        const int w4 = (v & 15) << 2;           // starting col of this float4
        const int sh = h  - off_y;
        const int sw = w4 - off_x;
        float4 r = make_float4(0.f, 0.f, 0.f, 0.f);
        if ((unsigned)sh < (unsigned)H_ && (unsigned)sw < (unsigned)W_) {
            r = src[(sh << 4) + (sw >> 2)];
        }
        dst[v] = r;
    }
}

extern "C" void kernel_launch(void* const* d_in, const int* in_sizes, int n_in,
                              void* d_out, int out_size, void* d_ws, size_t ws_size,
                              hipStream_t stream)
{
    const float* inp  = (const float*)d_in[0];
    const int*   offs = (const int*)d_in[1];
    float*       out  = (float*)d_out;

    dim3 grid(B_ * C_);   // 4608 blocks, one (b,c) plane each
    dim3 block(256);
    displace_kernel<<<grid, block, 0, stream>>>(inp, offs, out);
}

// Round 3
// 127.025 us; speedup vs baseline: 1.0099x; 1.0099x over previous
//
#include <hip/hip_runtime.h>

// DisplaceChannel: out[b,p,c,h,w] = in[b,p,c, h-off_y[p], w-off_x[p]] (0 if OOB)
// B=16, P=9, C/P=32 (C=288), H=W=64. Offsets are multiples of 32 -> 16B
// vectors stay aligned and validity is uniform within each vector.
//
// Pure streaming, zero reuse: read ~33.5 MB + write ~75.5 MB -> ~17 us floor
// at 6.3 TB/s. Nontemporal hints + batch the 4 loads before the 4 stores.

#define B_   16
#define C_   288
#define H_   64
#define W_   64

typedef float f32x4 __attribute__((ext_vector_type(4)));  // native vector: OK for nontemporal builtins

__global__ __launch_bounds__(256) void displace_kernel(
    const float* __restrict__ inp,
    const int*   __restrict__ offs,
    float*       __restrict__ out)
{
    const int bc = blockIdx.x;            // [0, B_*C_) -- one (b,c) plane
    const int c  = bc % C_;               // block-uniform
    const int p  = c >> 5;                // CHAN_PER_POS = 32
    const int off_x = offs[2 * p];
    const int off_y = offs[2 * p + 1];

    const f32x4* __restrict__ src = (const f32x4*)(inp + (size_t)bc * (H_ * W_));
    f32x4* __restrict__ dst       = (f32x4*)(out + (size_t)bc * (H_ * W_));

    // 1024 vectors per plane; 256 threads x 4 vectors each.
    f32x4 r[4];
    #pragma unroll
    for (int k = 0; k < 4; ++k) {
        const int v  = k * 256 + threadIdx.x;   // [0, 1024)
        const int h  = v >> 4;                  // row
        const int w4 = (v & 15) << 2;           // starting col of this vector
        const int sh = h  - off_y;
        const int sw = w4 - off_x;
        r[k] = (f32x4){0.f, 0.f, 0.f, 0.f};
        if ((unsigned)sh < (unsigned)H_ && (unsigned)sw < (unsigned)W_) {
            r[k] = __builtin_nontemporal_load(&src[(sh << 4) + (sw >> 2)]);
        }
    }
    #pragma unroll
    for (int k = 0; k < 4; ++k) {
        __builtin_nontemporal_store(r[k], &dst[k * 256 + threadIdx.x]);
    }
}

extern "C" void kernel_launch(void* const* d_in, const int* in_sizes, int n_in,
                              void* d_out, int out_size, void* d_ws, size_t ws_size,
                              hipStream_t stream)
{
    const float* inp  = (const float*)d_in[0];
    const int*   offs = (const int*)d_in[1];
    float*       out  = (float*)d_out;

    dim3 grid(B_ * C_);   // 4608 blocks, one (b,c) plane each
    dim3 block(256);
    displace_kernel<<<grid, block, 0, stream>>>(inp, offs, out);
}